// Round 5
// baseline (336.456 us; speedup 1.0000x reference)
//
#include <hip/hip_runtime.h>

#define N_USERS 100000
#define EMBED   128
#define QSTRIDE ((size_t)N_USERS * 32)   // one column-quarter of xt (bf16)

typedef __attribute__((ext_vector_type(8))) short bf16x8;
typedef __attribute__((ext_vector_type(4))) float f32x4;

// ---------------------------------------------------------------- row pointers
__global__ __launch_bounds__(256) void rowptr_kernel(const int* __restrict__ rows,
                                                     int* __restrict__ row_ptr,
                                                     int n_rows, int n_edges) {
  int r = blockIdx.x * blockDim.x + threadIdx.x;
  if (r > n_rows) return;
  int lo = 0, hi = n_edges;
  while (lo < hi) {
    int mid = (lo + hi) >> 1;
    if (rows[mid] < r) lo = mid + 1; else hi = mid;
  }
  row_ptr[r] = lo;
}

// ---------------------------------------------------------------- W -> Wt bf16
__global__ __launch_bounds__(256) void wconv_kernel(const float* __restrict__ W0,
                                                    const float* __restrict__ W1,
                                                    uint* __restrict__ Wt0,
                                                    uint* __restrict__ Wt1) {
  const float* W  = blockIdx.x ? W1 : W0;
  uint*        Wt = blockIdx.x ? Wt1 : Wt0;
  for (int idx = threadIdx.x; idx < 128 * 64; idx += 256) {
    int n = idx >> 6;
    int kp = idx & 63;
    float a = W[(2 * kp) * 128 + n];
    float b = W[(2 * kp + 1) * 128 + n];
    uint o;
    asm("v_cvt_pk_bf16_f32 %0, %1, %2" : "=v"(o) : "v"(a), "v"(b));
    Wt[n * 64 + kp] = o;
  }
}

// ---------------------------------------------------------------- MFMA GEMM
// Y(bf16, quarter-major [4][N][32]) = X @ W; optionally streams X -> Xcopy.
__global__ __launch_bounds__(256) void gemm_kernel(const float* __restrict__ X,
                                                   const ushort* __restrict__ Wt,
                                                   ushort* __restrict__ Y,
                                                   float* __restrict__ Xcopy) {
  const int tid  = threadIdx.x;
  const int wave = tid >> 6;
  const int lane = tid & 63;
  const int l15  = lane & 15;
  const int lg   = lane >> 4;                       // 0..3 (k-chunk)
  const int m    = blockIdx.x * 64 + wave * 16 + l15;
  const int mc   = m < N_USERS ? m : N_USERS - 1;
  const bool act = m < N_USERS;
  const float* xrow = X + (size_t)mc * EMBED;

  f32x4 acc[8];
  #pragma unroll
  for (int t = 0; t < 8; ++t) acc[t] = (f32x4){0.f, 0.f, 0.f, 0.f};

  #pragma unroll
  for (int s = 0; s < 4; ++s) {
    const int k0 = s * 32 + lg * 8;
    float4 xa = *(const float4*)(xrow + k0);
    float4 xb = *(const float4*)(xrow + k0 + 4);
    if (Xcopy && act) {
      *(float4*)(Xcopy + (size_t)m * EMBED + k0)     = xa;
      *(float4*)(Xcopy + (size_t)m * EMBED + k0 + 4) = xb;
    }
    union { bf16x8 v; uint u[4]; } bfr;
    asm("v_cvt_pk_bf16_f32 %0, %1, %2" : "=v"(bfr.u[0]) : "v"(xa.x), "v"(xa.y));
    asm("v_cvt_pk_bf16_f32 %0, %1, %2" : "=v"(bfr.u[1]) : "v"(xa.z), "v"(xa.w));
    asm("v_cvt_pk_bf16_f32 %0, %1, %2" : "=v"(bfr.u[2]) : "v"(xb.x), "v"(xb.y));
    asm("v_cvt_pk_bf16_f32 %0, %1, %2" : "=v"(bfr.u[3]) : "v"(xb.z), "v"(xb.w));
    #pragma unroll
    for (int nt = 0; nt < 8; ++nt) {
      union { bf16x8 v; uint4 u; } afr;
      afr.u = *(const uint4*)(Wt + (size_t)(nt * 16 + l15) * 128 + k0);
      acc[nt] = __builtin_amdgcn_mfma_f32_16x16x32_bf16(afr.v, bfr.v, acc[nt], 0, 0, 0);
    }
  }

  if (act) {
    #pragma unroll
    for (int nt = 0; nt < 8; ++nt) {
      uint2 o;
      asm("v_cvt_pk_bf16_f32 %0, %1, %2" : "=v"(o.x) : "v"(acc[nt][0]), "v"(acc[nt][1]));
      asm("v_cvt_pk_bf16_f32 %0, %1, %2" : "=v"(o.y) : "v"(acc[nt][2]), "v"(acc[nt][3]));
      // col c0 = nt*16 + lg*4  ->  quarter q = nt>>1, in-quarter col (nt&1)*16+lg*4
      ushort* dst = Y + (size_t)(nt >> 1) * QSTRIDE + (size_t)m * 32
                      + ((nt & 1) * 16 + lg * 4);
      *(uint2*)dst = o;
    }
  }
}

// ---------------------------------------------------------------- SpMM quarter
// OUT[r][q*32+j] = X[r][q*32+j] + sum_e vals[e] * bf16(XTq[cols[e]][j])
// 4 lanes per row (8 cols / 16B gather each), 64 rows per 256-thread block.
// XTq is one contiguous 6.4 MB quarter -> high per-XCD L2 residency.
#define FMA8(g, v)                                                     \
  do {                                                                 \
    acc[0] = fmaf((v), __uint_as_float((g).x << 16),         acc[0]);  \
    acc[1] = fmaf((v), __uint_as_float((g).x & 0xffff0000u), acc[1]);  \
    acc[2] = fmaf((v), __uint_as_float((g).y << 16),         acc[2]);  \
    acc[3] = fmaf((v), __uint_as_float((g).y & 0xffff0000u), acc[3]);  \
    acc[4] = fmaf((v), __uint_as_float((g).z << 16),         acc[4]);  \
    acc[5] = fmaf((v), __uint_as_float((g).z & 0xffff0000u), acc[5]);  \
    acc[6] = fmaf((v), __uint_as_float((g).w << 16),         acc[6]);  \
    acc[7] = fmaf((v), __uint_as_float((g).w & 0xffff0000u), acc[7]);  \
  } while (0)

__global__ __launch_bounds__(256) void spmm_q_kernel(const ushort* __restrict__ XTq,
                                                     const float* __restrict__ X,
                                                     const int* __restrict__ row_ptr,
                                                     const int* __restrict__ cols,
                                                     const float* __restrict__ vals,
                                                     float* __restrict__ OUT,
                                                     int q) {
  const int tid = threadIdx.x;
  const int l   = tid & 3;         // lane within row (8 cols each)
  const int g   = tid >> 2;        // 0..63 rows per block
  const int row = blockIdx.x * 64 + g;
  if (row >= N_USERS) return;
  const int start = row_ptr[row];
  const int end   = row_ptr[row + 1];
  const uint4* XT4 = (const uint4*)XTq;   // row c -> idx c*4 + l

  float acc[8];
  const float* xr = X + (size_t)row * EMBED + q * 32 + l * 8;
  {
    float4 r0 = *(const float4*)xr;
    float4 r1 = *(const float4*)(xr + 4);
    acc[0] = r0.x; acc[1] = r0.y; acc[2] = r0.z; acc[3] = r0.w;
    acc[4] = r1.x; acc[5] = r1.y; acc[6] = r1.z; acc[7] = r1.w;
  }

  int e = start;
  int e_pre = (start + 3) & ~3;
  if (e_pre > end) e_pre = end;
  for (; e < e_pre; ++e) {
    int   c = cols[e];
    float v = vals[e];
    uint4 gt = XT4[(size_t)c * 4 + l];
    FMA8(gt, v);
  }
  for (; e + 4 <= end; e += 4) {
    int4   c = *(const int4*)(cols + e);
    float4 v = *(const float4*)(vals + e);
    uint4 g0 = XT4[(size_t)c.x * 4 + l];
    uint4 g1 = XT4[(size_t)c.y * 4 + l];
    uint4 g2 = XT4[(size_t)c.z * 4 + l];
    uint4 g3 = XT4[(size_t)c.w * 4 + l];
    FMA8(g0, v.x);
    FMA8(g1, v.y);
    FMA8(g2, v.z);
    FMA8(g3, v.w);
  }
  for (; e < end; ++e) {
    int   c = cols[e];
    float v = vals[e];
    uint4 gt = XT4[(size_t)c * 4 + l];
    FMA8(gt, v);
  }

  float* orow = OUT + (size_t)row * EMBED + q * 32 + l * 8;
  float4 o0 = {acc[0], acc[1], acc[2], acc[3]};
  float4 o1 = {acc[4], acc[5], acc[6], acc[7]};
  *(float4*)orow       = o0;
  *(float4*)(orow + 4) = o1;
}

// ---------------------------------------------------------------- launch
extern "C" void kernel_launch(void* const* d_in, const int* in_sizes, int n_in,
                              void* d_out, int out_size, void* d_ws, size_t ws_size,
                              hipStream_t stream) {
  const float* user_embeds = (const float*)d_in[0];
  const int*   s_rows      = (const int*)d_in[1];
  const int*   s_cols      = (const int*)d_in[2];
  const float* s_values    = (const float*)d_in[3];
  const float* W0          = (const float*)d_in[4];
  const float* W1          = (const float*)d_in[5];
  float* out = (float*)d_out;

  const int n_edges = in_sizes[1];
  const size_t layer = (size_t)N_USERS * EMBED;

  char* ws = (char*)d_ws;
  ushort* xt      = (ushort*)ws;   ws += layer * sizeof(ushort);        // 25.6 MB
  ushort* Wt0     = (ushort*)ws;   ws += 128 * 128 * sizeof(ushort);
  ushort* Wt1     = (ushort*)ws;   ws += 128 * 128 * sizeof(ushort);
  int*    row_ptr = (int*)ws;

  rowptr_kernel<<<(N_USERS + 1 + 255) / 256, 256, 0, stream>>>(
      s_rows, row_ptr, N_USERS, n_edges);
  wconv_kernel<<<2, 256, 0, stream>>>(W0, W1, (uint*)Wt0, (uint*)Wt1);

  const ushort* Wtl[2] = {Wt0, Wt1};
  for (int l = 0; l < 2; ++l) {
    // Layer 0 reads the ORIGINAL input (d_out is zeroed by the harness).
    const float* Xl = (l == 0) ? user_embeds : (out + l * layer);
    gemm_kernel<<<(N_USERS + 63) / 64, 256, 0, stream>>>(
        Xl, Wtl[l], xt, l == 0 ? out : nullptr);
    // 4 sequential quarter passes: each gathers from one contiguous 6.4 MB
    // slice -> L2-resident working set; output column slices are disjoint.
    for (int q = 0; q < 4; ++q) {
      spmm_q_kernel<<<(N_USERS + 63) / 64, 256, 0, stream>>>(
          xt + (size_t)q * QSTRIDE, Xl, row_ptr, s_cols, s_values,
          out + (l + 1) * layer, q);
    }
  }
}

// Round 6
// 245.837 us; speedup vs baseline: 1.3686x; 1.3686x over previous
//
#include <hip/hip_runtime.h>

#define N_USERS 100000
#define EMBED   128

typedef __attribute__((ext_vector_type(8))) short bf16x8;
typedef __attribute__((ext_vector_type(4))) float f32x4;
typedef __attribute__((ext_vector_type(4))) uint  u32x4;

// ---------------------------------------------------------------- row pointers
__global__ __launch_bounds__(256) void rowptr_kernel(const int* __restrict__ rows,
                                                     int* __restrict__ row_ptr,
                                                     int n_rows, int n_edges) {
  int r = blockIdx.x * blockDim.x + threadIdx.x;
  if (r > n_rows) return;
  int lo = 0, hi = n_edges;
  while (lo < hi) {
    int mid = (lo + hi) >> 1;
    if (rows[mid] < r) lo = mid + 1; else hi = mid;
  }
  row_ptr[r] = lo;
}

// ---------------------------------------------------------------- W -> Wt bf16
// Wt[n][k] = bf16(W[k][n]); 64 uint per row (bf16 pairs along k).
__global__ __launch_bounds__(256) void wconv_kernel(const float* __restrict__ W0,
                                                    const float* __restrict__ W1,
                                                    uint* __restrict__ Wt0,
                                                    uint* __restrict__ Wt1) {
  const float* W  = blockIdx.x ? W1 : W0;
  uint*        Wt = blockIdx.x ? Wt1 : Wt0;
  for (int idx = threadIdx.x; idx < 128 * 64; idx += 256) {
    int n = idx >> 6;
    int kp = idx & 63;
    float a = W[(2 * kp) * 128 + n];
    float b = W[(2 * kp + 1) * 128 + n];
    uint o;
    asm("v_cvt_pk_bf16_f32 %0, %1, %2" : "=v"(o) : "v"(a), "v"(b));
    Wt[n * 64 + kp] = o;
  }
}

// ---------------------------------------------------------------- MFMA GEMM
// Y(bf16)[m][n] = (X @ W)[m][n], X staged via LDS (coalesced global reads).
// Block: 256 thr / 4 waves / 64 rows. Optionally streams X -> Xcopy (f32).
#define XS_STRIDE 136   // bf16 elems per LDS row (128 + 8 pad -> 272B stride)

__global__ __launch_bounds__(256) void gemm_kernel(const float* __restrict__ X,
                                                   const ushort* __restrict__ Wt,
                                                   ushort* __restrict__ Y,
                                                   float* __restrict__ Xcopy) {
  __shared__ ushort Xs[64 * XS_STRIDE];     // 17.4 KB
  const int tid  = threadIdx.x;
  const int wave = tid >> 6;
  const int lane = tid & 63;
  const int l15  = lane & 15;
  const int lg   = lane >> 4;               // 0..3 (k-chunk)
  const int row0 = blockIdx.x * 64;

  // ---- stage X tile: coalesced float4 loads, bf16 convert, LDS write.
  // 64 rows x 32 float4 = 2048 float4; 8 iters x 256 threads.
  #pragma unroll
  for (int i = 0; i < 8; ++i) {
    int idx4 = i * 256 + tid;               // float4 index in tile
    int r    = idx4 >> 5;                   // tile row
    int kc   = idx4 & 31;                   // float4 index in row
    int gr   = row0 + r;
    int grc  = gr < N_USERS ? gr : N_USERS - 1;
    float4 v = *(const float4*)(X + (size_t)grc * EMBED + kc * 4);
    if (Xcopy && gr < N_USERS)
      *(float4*)(Xcopy + (size_t)gr * EMBED + kc * 4) = v;
    uint2 p;
    asm("v_cvt_pk_bf16_f32 %0, %1, %2" : "=v"(p.x) : "v"(v.x), "v"(v.y));
    asm("v_cvt_pk_bf16_f32 %0, %1, %2" : "=v"(p.y) : "v"(v.z), "v"(v.w));
    *(uint2*)(Xs + r * XS_STRIDE + kc * 4) = p;
  }
  __syncthreads();

  const int tr = wave * 16 + l15;           // tile row this lane computes
  const int m  = row0 + tr;

  f32x4 acc[8];
  #pragma unroll
  for (int t = 0; t < 8; ++t) acc[t] = (f32x4){0.f, 0.f, 0.f, 0.f};

  #pragma unroll
  for (int s = 0; s < 4; ++s) {
    const int k0 = s * 32 + lg * 8;
    union { bf16x8 v; uint4 u; } bfr;
    bfr.u = *(const uint4*)(Xs + tr * XS_STRIDE + k0);
    #pragma unroll
    for (int nt = 0; nt < 8; ++nt) {
      union { bf16x8 v; uint4 u; } afr;
      afr.u = *(const uint4*)(Wt + (size_t)(nt * 16 + l15) * 128 + k0);
      acc[nt] = __builtin_amdgcn_mfma_f32_16x16x32_bf16(afr.v, bfr.v, acc[nt], 0, 0, 0);
    }
  }

  if (m < N_USERS) {
    ushort* yrow = Y + (size_t)m * EMBED;
    #pragma unroll
    for (int nt = 0; nt < 8; ++nt) {
      uint2 o;
      asm("v_cvt_pk_bf16_f32 %0, %1, %2" : "=v"(o.x) : "v"(acc[nt][0]), "v"(acc[nt][1]));
      asm("v_cvt_pk_bf16_f32 %0, %1, %2" : "=v"(o.y) : "v"(acc[nt][2]), "v"(acc[nt][3]));
      *(uint2*)(yrow + nt * 16 + lg * 4) = o;
    }
  }
}

// ---------------------------------------------------------------- SpMM + residual
// OUT[r] = X[r] + sum_e vals[e] * bf16(XT[cols[e]])
// 16 lanes per row (8 cols / 16B gather each), 16 rows per 256-thread block.
__device__ __forceinline__ void fma8(float* acc, u32x4 g, float v) {
  acc[0] = fmaf(v, __uint_as_float(g[0] << 16),         acc[0]);
  acc[1] = fmaf(v, __uint_as_float(g[0] & 0xffff0000u), acc[1]);
  acc[2] = fmaf(v, __uint_as_float(g[1] << 16),         acc[2]);
  acc[3] = fmaf(v, __uint_as_float(g[1] & 0xffff0000u), acc[3]);
  acc[4] = fmaf(v, __uint_as_float(g[2] << 16),         acc[4]);
  acc[5] = fmaf(v, __uint_as_float(g[2] & 0xffff0000u), acc[5]);
  acc[6] = fmaf(v, __uint_as_float(g[3] << 16),         acc[6]);
  acc[7] = fmaf(v, __uint_as_float(g[3] & 0xffff0000u), acc[7]);
}

__global__ __launch_bounds__(256) void spmm_kernel(const ushort* __restrict__ XT,
                                                   const float* __restrict__ X,
                                                   const int* __restrict__ row_ptr,
                                                   const int* __restrict__ cols,
                                                   const float* __restrict__ vals,
                                                   float* __restrict__ OUT) {
  const int tid = threadIdx.x;
  const int l   = tid & 15;        // 8 cols / 16B per lane
  const int rg  = tid >> 4;        // 16 rows per block
  const int row = blockIdx.x * 16 + rg;
  if (row >= N_USERS) return;
  const int start = row_ptr[row];
  const int end   = row_ptr[row + 1];
  const u32x4* XT4 = (const u32x4*)XT;   // row stride = 16

  float acc[8];
  {
    float4 r0 = *(const float4*)(X + (size_t)row * EMBED + l * 8);
    float4 r1 = *(const float4*)(X + (size_t)row * EMBED + l * 8 + 4);
    acc[0] = r0.x; acc[1] = r0.y; acc[2] = r0.z; acc[3] = r0.w;
    acc[4] = r1.x; acc[5] = r1.y; acc[6] = r1.z; acc[7] = r1.w;
  }

  int e = start;
  int e_pre = (start + 3) & ~3;    // peel to int4 alignment
  if (e_pre > end) e_pre = end;
  for (; e < e_pre; ++e) {
    u32x4 g = XT4[(size_t)cols[e] * 16 + l];
    fma8(acc, g, vals[e]);
  }
  for (; e + 8 <= end; e += 8) {   // deep unroll: 8 gathers in flight
    int4   ca = *(const int4*)(cols + e);
    int4   cb = *(const int4*)(cols + e + 4);
    float4 va = *(const float4*)(vals + e);
    float4 vb = *(const float4*)(vals + e + 4);
    u32x4 g0 = XT4[(size_t)ca.x * 16 + l];
    u32x4 g1 = XT4[(size_t)ca.y * 16 + l];
    u32x4 g2 = XT4[(size_t)ca.z * 16 + l];
    u32x4 g3 = XT4[(size_t)ca.w * 16 + l];
    u32x4 g4 = XT4[(size_t)cb.x * 16 + l];
    u32x4 g5 = XT4[(size_t)cb.y * 16 + l];
    u32x4 g6 = XT4[(size_t)cb.z * 16 + l];
    u32x4 g7 = XT4[(size_t)cb.w * 16 + l];
    fma8(acc, g0, va.x); fma8(acc, g1, va.y);
    fma8(acc, g2, va.z); fma8(acc, g3, va.w);
    fma8(acc, g4, vb.x); fma8(acc, g5, vb.y);
    fma8(acc, g6, vb.z); fma8(acc, g7, vb.w);
  }
  for (; e + 4 <= end; e += 4) {
    int4   ca = *(const int4*)(cols + e);
    float4 va = *(const float4*)(vals + e);
    u32x4 g0 = XT4[(size_t)ca.x * 16 + l];
    u32x4 g1 = XT4[(size_t)ca.y * 16 + l];
    u32x4 g2 = XT4[(size_t)ca.z * 16 + l];
    u32x4 g3 = XT4[(size_t)ca.w * 16 + l];
    fma8(acc, g0, va.x); fma8(acc, g1, va.y);
    fma8(acc, g2, va.z); fma8(acc, g3, va.w);
  }
  for (; e < end; ++e) {
    u32x4 g = XT4[(size_t)cols[e] * 16 + l];
    fma8(acc, g, vals[e]);
  }

  float4 o0 = {acc[0], acc[1], acc[2], acc[3]};
  float4 o1 = {acc[4], acc[5], acc[6], acc[7]};
  *(float4*)(OUT + (size_t)row * EMBED + l * 8)     = o0;
  *(float4*)(OUT + (size_t)row * EMBED + l * 8 + 4) = o1;
}

// ---------------------------------------------------------------- launch
extern "C" void kernel_launch(void* const* d_in, const int* in_sizes, int n_in,
                              void* d_out, int out_size, void* d_ws, size_t ws_size,
                              hipStream_t stream) {
  const float* user_embeds = (const float*)d_in[0];
  const int*   s_rows      = (const int*)d_in[1];
  const int*   s_cols      = (const int*)d_in[2];
  const float* s_values    = (const float*)d_in[3];
  const float* W0          = (const float*)d_in[4];
  const float* W1          = (const float*)d_in[5];
  float* out = (float*)d_out;

  const int n_edges = in_sizes[1];
  const size_t layer = (size_t)N_USERS * EMBED;

  char* ws = (char*)d_ws;
  ushort* xt      = (ushort*)ws;   ws += layer * sizeof(ushort);        // 25.6 MB
  ushort* Wt0     = (ushort*)ws;   ws += 128 * 128 * sizeof(ushort);
  ushort* Wt1     = (ushort*)ws;   ws += 128 * 128 * sizeof(ushort);
  int*    row_ptr = (int*)ws;

  rowptr_kernel<<<(N_USERS + 1 + 255) / 256, 256, 0, stream>>>(
      s_rows, row_ptr, N_USERS, n_edges);
  wconv_kernel<<<2, 256, 0, stream>>>(W0, W1, (uint*)Wt0, (uint*)Wt1);

  const ushort* Wtl[2] = {Wt0, Wt1};
  for (int l = 0; l < 2; ++l) {
    // Layer 0 reads the ORIGINAL input (d_out is zeroed by the harness);
    // gemm0 streams user_embeds -> out[0] during its coalesced staging loop.
    const float* Xl = (l == 0) ? user_embeds : (out + l * layer);
    gemm_kernel<<<(N_USERS + 63) / 64, 256, 0, stream>>>(
        Xl, Wtl[l], xt, l == 0 ? out : nullptr);
    spmm_kernel<<<(N_USERS + 15) / 16, 256, 0, stream>>>(
        xt, Xl, row_ptr, s_cols, s_values, out + (l + 1) * layer);
  }
}